// Round 3
// baseline (3764.074 us; speedup 1.0000x reference)
//
#include <hip/hip_runtime.h>

#define HID 6
#define HS  8                   // padded hidden stride for intermediate h buffers
#define NUM_GRAPHS 1000
#define SCAN_B 1024
#define NBUCK 256
#define P1_CHUNK 4096
#define P1_PERT  16             // P1_CHUNK / 256
#define AGG_EPB  4096
#define AGG_PERT 16             // AGG_EPB / 256
#define MAXSPAN  1024           // LDS node capacity in agg_kernel (24KB)

// ===========================================================================
// degree histogram
// ===========================================================================
__global__ void hist_kernel(const int* __restrict__ dst, int* __restrict__ deg, int E) {
    long i = ((long)blockIdx.x * blockDim.x + threadIdx.x) * 4;
    if (i + 4 <= E) {
        int4 v = *(const int4*)(dst + i);
        atomicAdd(&deg[v.x], 1);
        atomicAdd(&deg[v.y], 1);
        atomicAdd(&deg[v.z], 1);
        atomicAdd(&deg[v.w], 1);
    } else {
        for (long e = i; e < E; ++e) atomicAdd(&deg[dst[e]], 1);
    }
}

// in-place exclusive scan within 1024-blocks
__global__ void scan_block_kernel(int* __restrict__ data, int* __restrict__ blockSums, int N) {
    __shared__ int tmp[SCAN_B];
    int t = threadIdx.x;
    int i = blockIdx.x * SCAN_B + t;
    int v = (i < N) ? data[i] : 0;
    tmp[t] = v;
    __syncthreads();
    for (int off = 1; off < SCAN_B; off <<= 1) {
        int a = (t >= off) ? tmp[t - off] : 0;
        __syncthreads();
        tmp[t] += a;
        __syncthreads();
    }
    if (i < N) data[i] = tmp[t] - v;
    if (blockSums && t == SCAN_B - 1) blockSums[blockIdx.x] = tmp[SCAN_B - 1];
}

__global__ void scan_finish_kernel(const int* __restrict__ scanned,
                                   const int* __restrict__ blockOffsets,
                                   int* __restrict__ rowStart, int* __restrict__ cursor,
                                   int N, int E) {
    int i = blockIdx.x * blockDim.x + threadIdx.x;
    if (i < N) {
        int v = scanned[i] + blockOffsets[i >> 10];
        rowStart[i] = v;
        cursor[i] = v;
    }
    if (i == 0) rowStart[N] = E;
}

__global__ void bucket_base_kernel(const int* __restrict__ rowStart, int* __restrict__ gcursor,
                                   int N, int bshift) {
    int b = threadIdx.x;  // one block of 256
    size_t lo = (size_t)b << bshift;
    if (lo > (size_t)N) lo = N;
    gcursor[b] = rowStart[lo];
}

// ===========================================================================
// pass 1: bin edges by dst>>bshift into bucket-contiguous tmp arrays
// ===========================================================================
__global__ void __launch_bounds__(256) pass1_kernel(
        const int* __restrict__ src, const int* __restrict__ dst,
        const float* __restrict__ ea,
        int* __restrict__ gcursor,
        int* __restrict__ tmp_src, int* __restrict__ tmp_dst, float* __restrict__ tmp_ea,
        int E, int bshift) {
    __shared__ int hist[NBUCK];
    __shared__ int base[NBUCK];
    int t = threadIdx.x;
    long e0 = (long)blockIdx.x * P1_CHUNK;

    hist[t] = 0;
    __syncthreads();

    int d[P1_PERT];
#pragma unroll
    for (int j = 0; j < P1_PERT; ++j) {
        long e = e0 + t + (long)j * 256;
        d[j] = (e < E) ? dst[e] : -1;
        if (d[j] >= 0) atomicAdd(&hist[d[j] >> bshift], 1);
    }
    __syncthreads();

    int hcnt = hist[t];
    int myb = hcnt ? atomicAdd(&gcursor[t], hcnt) : 0;
    __syncthreads();          // everyone done reading hist
    base[t] = myb;
    hist[t] = 0;              // reuse as per-block offset counter
    __syncthreads();

#pragma unroll
    for (int j = 0; j < P1_PERT; ++j) {
        long e = e0 + t + (long)j * 256;
        if (e >= E) continue;
        int b = d[j] >> bshift;
        int pos = base[b] + atomicAdd(&hist[b], 1);
        tmp_src[pos] = src[e];
        tmp_dst[pos] = d[j];
        const float2* s = (const float2*)(ea + (size_t)e * HID);
        float2 a0 = s[0], a1 = s[1], a2 = s[2];
        float2* o = (float2*)(tmp_ea + (size_t)pos * HID);
        o[0] = a0; o[1] = a1; o[2] = a2;
    }
}

// ===========================================================================
// pass 2: within-bucket scatter to exact dst-sorted position (writes stay in
// ~1MB bucket regions -> cache-absorbed)
// ===========================================================================
__global__ void pass2_kernel(const int* __restrict__ tmp_src, const int* __restrict__ tmp_dst,
                             const float* __restrict__ tmp_ea,
                             int* __restrict__ cursor,
                             int* __restrict__ src_perm, int* __restrict__ dst_perm,
                             float* __restrict__ ea_perm, int E) {
    long e = (long)blockIdx.x * blockDim.x + threadIdx.x;
    if (e >= E) return;
    int dd = tmp_dst[e];
    int pos = atomicAdd(&cursor[dd], 1);
    src_perm[pos] = tmp_src[e];
    dst_perm[pos] = dd;
    const float2* s = (const float2*)(tmp_ea + (size_t)e * HID);
    float2 a0 = s[0], a1 = s[1], a2 = s[2];
    float2* o = (float2*)(ea_perm + (size_t)pos * HID);
    o[0] = a0; o[1] = a1; o[2] = a2;
}

// direct one-pass scatter (tier B/C fallback)
__global__ void scatter_direct_kernel(const int* __restrict__ src, const int* __restrict__ dst,
                                      const float* __restrict__ ea,
                                      int* __restrict__ cursor,
                                      int* __restrict__ src_perm, int* __restrict__ dst_perm,
                                      float* __restrict__ ea_perm, int E, int writeDst) {
    long e = (long)blockIdx.x * blockDim.x + threadIdx.x;
    if (e >= E) return;
    int dd = dst[e];
    int pos = atomicAdd(&cursor[dd], 1);
    src_perm[pos] = src[e];
    if (writeDst) dst_perm[pos] = dd;
    const float2* s = (const float2*)(ea + (size_t)e * HID);
    float2 a0 = s[0], a1 = s[1], a2 = s[2];
    float2* o = (float2*)(ea_perm + (size_t)pos * HID);
    o[0] = a0; o[1] = a1; o[2] = a2;
}

// ===========================================================================
// edge-parallel aggregation: thread owns 16 consecutive sorted edges,
// run-combines in registers, stages block's node span in LDS.
// ===========================================================================
__global__ void __launch_bounds__(256) agg_kernel(
        const float* __restrict__ h, int hstride,
        const float* __restrict__ ea_perm,
        const int* __restrict__ src_perm, const int* __restrict__ dst_perm,
        float* __restrict__ agg, int E) {
    __shared__ float sagg[MAXSPAN * HID];
    int t = threadIdx.x;
    long e0 = (long)blockIdx.x * AGG_EPB;
    long eEnd = e0 + AGG_EPB; if (eEnd > E) eEnd = E;
    int nodeLo = dst_perm[e0];
    int nodeHi = dst_perm[eEnd - 1];
    int span = nodeHi - nodeLo + 1;
    bool useLds = (span <= MAXSPAN);
    if (useLds) for (int i = t; i < span * HID; i += 256) sagg[i] = 0.0f;
    __syncthreads();

    long myBeg = e0 + (long)t * AGG_PERT;
    long myEnd = myBeg + AGG_PERT; if (myEnd > eEnd) myEnd = eEnd;
    float a0 = 0, a1 = 0, a2 = 0, a3 = 0, a4 = 0, a5 = 0;
    int cur = -1;

#define FLUSH_ACC                                                            \
    do {                                                                     \
        if (useLds) {                                                        \
            float* p = sagg + (size_t)(cur - nodeLo) * HID;                  \
            atomicAdd(p + 0, a0); atomicAdd(p + 1, a1); atomicAdd(p + 2, a2);\
            atomicAdd(p + 3, a3); atomicAdd(p + 4, a4); atomicAdd(p + 5, a5);\
        } else {                                                             \
            float* p = agg + (size_t)cur * HID;                              \
            atomicAdd(p + 0, a0); atomicAdd(p + 1, a1); atomicAdd(p + 2, a2);\
            atomicAdd(p + 3, a3); atomicAdd(p + 4, a4); atomicAdd(p + 5, a5);\
        }                                                                    \
    } while (0)

    for (long e = myBeg; e < myEnd; ++e) {
        int dd = dst_perm[e];
        if (dd != cur) {
            if (cur >= 0) FLUSH_ACC;
            cur = dd;
            a0 = a1 = a2 = a3 = a4 = a5 = 0.0f;
        }
        int s = src_perm[e];
        const float2* hs = (const float2*)(h + (size_t)s * hstride);
        const float2* ap = (const float2*)(ea_perm + (size_t)e * HID);
        float2 b0 = hs[0], b1 = hs[1], b2 = hs[2];
        float2 q0 = ap[0], q1 = ap[1], q2 = ap[2];
        a0 += fmaxf(b0.x + q0.x, 0.0f);
        a1 += fmaxf(b0.y + q0.y, 0.0f);
        a2 += fmaxf(b1.x + q1.x, 0.0f);
        a3 += fmaxf(b1.y + q1.y, 0.0f);
        a4 += fmaxf(b2.x + q2.x, 0.0f);
        a5 += fmaxf(b2.y + q2.y, 0.0f);
    }
    if (cur >= 0) FLUSH_ACC;
#undef FLUSH_ACC
    __syncthreads();

    if (useLds) {
        for (int n = t; n < span; n += 256) {
            float* gp = agg + (size_t)(nodeLo + n) * HID;
            const float* sp = sagg + (size_t)n * HID;
            if (n == 0 || n == span - 1) {
#pragma unroll
                for (int j = 0; j < HID; ++j) atomicAdd(gp + j, sp[j]);
            } else {
                float2* g2 = (float2*)gp; const float2* s2 = (const float2*)sp;
                g2[0] = s2[0]; g2[1] = s2[1]; g2[2] = s2[2];
            }
        }
    }
}

// ===========================================================================
// node update: out = (h + agg) @ W + b  (strided h layouts)
// ===========================================================================
__global__ void node_kernel(const float* __restrict__ h, int hstride,
                            const float* __restrict__ agg,
                            const float* __restrict__ W, const float* __restrict__ b,
                            float* __restrict__ out, int ostride, int N, int do_relu) {
    __shared__ float sW[HID * HID];
    __shared__ float sb[HID];
    if (threadIdx.x < HID * HID) sW[threadIdx.x] = W[threadIdx.x];
    if (threadIdx.x < HID) sb[threadIdx.x] = b[threadIdx.x];
    __syncthreads();
    int i = blockIdx.x * blockDim.x + threadIdx.x;
    if (i >= N) return;
    const float2* hp = (const float2*)(h + (size_t)i * hstride);
    const float2* ap = (const float2*)(agg + (size_t)i * HID);
    float2 v0 = hp[0], v1 = hp[1], v2 = hp[2];
    float2 g0 = ap[0], g1 = ap[1], g2 = ap[2];
    float tv[HID];
    tv[0] = v0.x + g0.x; tv[1] = v0.y + g0.y;
    tv[2] = v1.x + g1.x; tv[3] = v1.y + g1.y;
    tv[4] = v2.x + g2.x; tv[5] = v2.y + g2.y;
    float o[HID];
#pragma unroll
    for (int d = 0; d < HID; ++d) o[d] = sb[d];
#pragma unroll
    for (int k = 0; k < HID; ++k)
#pragma unroll
        for (int d = 0; d < HID; ++d) o[d] += tv[k] * sW[k * HID + d];
    if (do_relu)
#pragma unroll
        for (int d = 0; d < HID; ++d) o[d] = fmaxf(o[d], 0.0f);
    float2* op = (float2*)(out + (size_t)i * ostride);
    op[0] = make_float2(o[0], o[1]);
    op[1] = make_float2(o[2], o[3]);
    op[2] = make_float2(o[4], o[5]);
}

// tier C: fused node-gather layer (round-2 structure, stride-aware)
__global__ void layer_gather_kernel(const float* __restrict__ h, int hstride,
                                    const float* __restrict__ ea_perm,
                                    const int* __restrict__ src_perm,
                                    const int* __restrict__ rowStart,
                                    const float* __restrict__ W, const float* __restrict__ b,
                                    float* __restrict__ out, int ostride, int N, int do_relu) {
    __shared__ float sW[HID * HID];
    __shared__ float sb[HID];
    if (threadIdx.x < HID * HID) sW[threadIdx.x] = W[threadIdx.x];
    if (threadIdx.x < HID) sb[threadIdx.x] = b[threadIdx.x];
    __syncthreads();
    int i = blockIdx.x * blockDim.x + threadIdx.x;
    if (i >= N) return;
    int beg = rowStart[i], end = rowStart[i + 1];
    float tv[HID];
    {
        const float2* hp = (const float2*)(h + (size_t)i * hstride);
        float2 h0 = hp[0], h1 = hp[1], h2 = hp[2];
        tv[0] = h0.x; tv[1] = h0.y; tv[2] = h1.x; tv[3] = h1.y; tv[4] = h2.x; tv[5] = h2.y;
    }
    for (int k = beg; k < end; ++k) {
        int s = src_perm[k];
        const float2* hs = (const float2*)(h + (size_t)s * hstride);
        const float2* ap = (const float2*)(ea_perm + (size_t)k * HID);
        float2 b0 = hs[0], b1 = hs[1], b2 = hs[2];
        float2 q0 = ap[0], q1 = ap[1], q2 = ap[2];
        tv[0] += fmaxf(b0.x + q0.x, 0.0f);
        tv[1] += fmaxf(b0.y + q0.y, 0.0f);
        tv[2] += fmaxf(b1.x + q1.x, 0.0f);
        tv[3] += fmaxf(b1.y + q1.y, 0.0f);
        tv[4] += fmaxf(b2.x + q2.x, 0.0f);
        tv[5] += fmaxf(b2.y + q2.y, 0.0f);
    }
    float o[HID];
#pragma unroll
    for (int d = 0; d < HID; ++d) o[d] = sb[d];
#pragma unroll
    for (int k = 0; k < HID; ++k)
#pragma unroll
        for (int d = 0; d < HID; ++d) o[d] += tv[k] * sW[k * HID + d];
    if (do_relu)
#pragma unroll
        for (int d = 0; d < HID; ++d) o[d] = fmaxf(o[d], 0.0f);
    float2* op = (float2*)(out + (size_t)i * ostride);
    op[0] = make_float2(o[0], o[1]);
    op[1] = make_float2(o[2], o[3]);
    op[2] = make_float2(o[4], o[5]);
}

// tier D: atomic edge pass
__global__ void edge_kernel(const float* __restrict__ h, int hstride,
                            const float* __restrict__ edge_attr,
                            const int* __restrict__ src, const int* __restrict__ dst,
                            float* __restrict__ agg, int E) {
    long e = (long)blockIdx.x * blockDim.x + threadIdx.x;
    if (e >= E) return;
    int s = src[e], d = dst[e];
    const float2* ea = (const float2*)(edge_attr + (size_t)e * HID);
    const float2* hs = (const float2*)(h + (size_t)s * hstride);
    float2 a0 = ea[0], a1 = ea[1], a2 = ea[2];
    float2 h0 = hs[0], h1 = hs[1], h2 = hs[2];
    float* ag = agg + (size_t)d * HID;
    atomicAdd(ag + 0, fmaxf(h0.x + a0.x, 0.0f));
    atomicAdd(ag + 1, fmaxf(h0.y + a0.y, 0.0f));
    atomicAdd(ag + 2, fmaxf(h1.x + a1.x, 0.0f));
    atomicAdd(ag + 3, fmaxf(h1.y + a1.y, 0.0f));
    atomicAdd(ag + 4, fmaxf(h2.x + a2.x, 0.0f));
    atomicAdd(ag + 5, fmaxf(h2.y + a2.y, 0.0f));
}

// ===========================================================================
// pool + output
// ===========================================================================
__global__ void pool_kernel(const float* __restrict__ h, int hstride,
                            const int* __restrict__ batch,
                            float* __restrict__ sums, float* __restrict__ cnts, int N) {
    int i = blockIdx.x * blockDim.x + threadIdx.x;
    int lane = threadIdx.x & 63;
    bool active = (i < N);
    float v[HID];
    int g = -1;
    if (active) {
        g = batch[i];
        const float2* hp = (const float2*)(h + (size_t)i * hstride);
        float2 v0 = hp[0], v1 = hp[1], v2 = hp[2];
        v[0] = v0.x; v[1] = v0.y; v[2] = v1.x; v[3] = v1.y; v[4] = v2.x; v[5] = v2.y;
    } else {
#pragma unroll
        for (int d = 0; d < HID; ++d) v[d] = 0.0f;
    }
    int g0 = __shfl(g, 0);
    bool uniform = __all(active) && __all(g == g0);
    if (uniform) {
#pragma unroll
        for (int d = 0; d < HID; ++d) {
            float s = v[d];
            for (int off = 32; off > 0; off >>= 1) s += __shfl_down(s, off);
            if (lane == 0) atomicAdd(&sums[(size_t)g0 * HID + d], s);
        }
        if (lane == 0) atomicAdd(&cnts[g0], 64.0f);
    } else if (active) {
#pragma unroll
        for (int d = 0; d < HID; ++d) atomicAdd(&sums[(size_t)g * HID + d], v[d]);
        atomicAdd(&cnts[g], 1.0f);
    }
}

__global__ void out_kernel(const float* __restrict__ sums, const float* __restrict__ cnts,
                           const float* __restrict__ Wl, const float* __restrict__ bl,
                           float* __restrict__ out) {
    int gI = blockIdx.x * blockDim.x + threadIdx.x;
    if (gI >= NUM_GRAPHS) return;
    float c = fmaxf(cnts[gI], 1.0f);
    float acc = bl[0];
#pragma unroll
    for (int d = 0; d < HID; ++d) acc += (sums[(size_t)gI * HID + d] / c) * Wl[d];
    out[gI] = acc;
}

// ===========================================================================
extern "C" void kernel_launch(void* const* d_in, const int* in_sizes, int n_in,
                              void* d_out, int out_size, void* d_ws, size_t ws_size,
                              hipStream_t stream) {
    const float* x         = (const float*)d_in[0];
    const int*   eidx      = (const int*)d_in[1];
    const float* edge_attr = (const float*)d_in[2];
    const int*   batch     = (const int*)d_in[3];
    const float* W1 = (const float*)d_in[4];
    const float* b1 = (const float*)d_in[5];
    const float* W2 = (const float*)d_in[6];
    const float* b2 = (const float*)d_in[7];
    const float* W3 = (const float*)d_in[8];
    const float* b3 = (const float*)d_in[9];
    const float* Wl = (const float*)d_in[10];
    const float* bl = (const float*)d_in[11];

    const int N = in_sizes[0] / HID;
    const int E = in_sizes[1] / 2;
    const int* src = eidx;
    const int* dst = eidx + E;

    const int TB = 256;
    const int nbl  = (N + TB - 1) / TB;
    const int ebl  = (E + TB - 1) / TB;
    const int p1bl = (E + P1_CHUNK - 1) / P1_CHUNK;
    const int agbl = (E + AGG_EPB - 1) / AGG_EPB;
    const int scanBlocks = (N + SCAN_B - 1) / SCAN_B;
    const bool canScan = (scanBlocks <= SCAN_B);

    int bshift = 0;
    while ((((long)N + (1L << bshift) - 1) >> bshift) > NBUCK) bshift++;

    const size_t szPad = (size_t)N * HS * sizeof(float);     // 32MB
    const size_t szAgg = (size_t)N * HID * sizeof(float);    // 24MB
    const size_t szEa  = (size_t)E * HID * sizeof(float);    // 288MB
    const size_t szInt = (size_t)E * sizeof(int);            // 48MB

    char* w = (char*)d_ws;
    size_t off = 0;
    auto alloc = [&](size_t bytes) { void* p = w + off; off += (bytes + 255) & ~(size_t)255; return p; };

    // fixed small/medium allocations
    float* ea_perm  = (float*)alloc(szEa);
    int*   src_perm = (int*)alloc(szInt);
    int*   deg      = (int*)alloc((size_t)N * sizeof(int));
    int*   rowStart = (int*)alloc((size_t)(N + 2) * sizeof(int));
    int*   cursor   = (int*)alloc((size_t)N * sizeof(int));
    int*   blockSums= (int*)alloc((size_t)SCAN_B * sizeof(int));
    int*   gcursor  = (int*)alloc((size_t)NBUCK * sizeof(int));
    float* sums     = (float*)alloc((size_t)NUM_GRAPHS * HID * sizeof(float));
    float* cnts     = (float*)alloc((size_t)NUM_GRAPHS * sizeof(float));
    size_t coreOff  = off;

    // tier C: + hA, hB
    float* hA = (float*)alloc(szPad);
    float* hB = (float*)alloc(szPad);
    size_t tierCneed = off;

    // tier B: + dst_perm, agg
    int*   dst_perm = (int*)alloc(szInt);
    float* agg      = (float*)alloc(szAgg);
    size_t tierBneed = off;

    // tier A: tmp region (aliases nothing live at the same time; appended)
    float* tmp_ea  = (float*)alloc(szEa);
    int*   tmp_src = (int*)alloc(szInt);
    int*   tmp_dst = (int*)alloc(szInt);
    size_t tierAneed = off;

    (void)coreOff;

    const float* hIn = nullptr; int hInStride = 0;  // final h for pooling

    if (canScan && ws_size >= tierBneed) {
        // ---- CSR build (common to A and B) ----
        hipMemsetAsync(deg, 0, (size_t)N * sizeof(int), stream);
        hipMemsetAsync(blockSums, 0, (size_t)SCAN_B * sizeof(int), stream);
        hist_kernel<<<(E / 4 + TB - 1) / TB + 1, TB, 0, stream>>>(dst, deg, E);
        scan_block_kernel<<<scanBlocks, SCAN_B, 0, stream>>>(deg, blockSums, N);
        scan_block_kernel<<<1, SCAN_B, 0, stream>>>(blockSums, nullptr, scanBlocks);
        scan_finish_kernel<<<nbl, TB, 0, stream>>>(deg, blockSums, rowStart, cursor, N, E);

        if (ws_size >= tierAneed) {
            // ---- tier A: two-pass binned permute ----
            bucket_base_kernel<<<1, NBUCK, 0, stream>>>(rowStart, gcursor, N, bshift);
            pass1_kernel<<<p1bl, TB, 0, stream>>>(src, dst, edge_attr, gcursor,
                                                  tmp_src, tmp_dst, tmp_ea, E, bshift);
            pass2_kernel<<<ebl, TB, 0, stream>>>(tmp_src, tmp_dst, tmp_ea, cursor,
                                                 src_perm, dst_perm, ea_perm, E);
        } else {
            // ---- tier B: direct scatter ----
            scatter_direct_kernel<<<ebl, TB, 0, stream>>>(src, dst, edge_attr, cursor,
                                                          src_perm, dst_perm, ea_perm, E, 1);
        }

        // ---- edge-parallel layers ----
        hipMemsetAsync(agg, 0, szAgg, stream);
        agg_kernel<<<agbl, TB, 0, stream>>>(x, HID, ea_perm, src_perm, dst_perm, agg, E);
        node_kernel<<<nbl, TB, 0, stream>>>(x, HID, agg, W1, b1, hA, HS, N, 1);

        hipMemsetAsync(agg, 0, szAgg, stream);
        agg_kernel<<<agbl, TB, 0, stream>>>(hA, HS, ea_perm, src_perm, dst_perm, agg, E);
        node_kernel<<<nbl, TB, 0, stream>>>(hA, HS, agg, W2, b2, hB, HS, N, 1);

        hipMemsetAsync(agg, 0, szAgg, stream);
        agg_kernel<<<agbl, TB, 0, stream>>>(hB, HS, ea_perm, src_perm, dst_perm, agg, E);
        node_kernel<<<nbl, TB, 0, stream>>>(hB, HS, agg, W3, b3, hA, HS, N, 0);

        hIn = hA; hInStride = HS;
    } else if (canScan && ws_size >= tierCneed) {
        // ---- tier C: direct scatter + node-gather layers ----
        hipMemsetAsync(deg, 0, (size_t)N * sizeof(int), stream);
        hipMemsetAsync(blockSums, 0, (size_t)SCAN_B * sizeof(int), stream);
        hist_kernel<<<(E / 4 + TB - 1) / TB + 1, TB, 0, stream>>>(dst, deg, E);
        scan_block_kernel<<<scanBlocks, SCAN_B, 0, stream>>>(deg, blockSums, N);
        scan_block_kernel<<<1, SCAN_B, 0, stream>>>(blockSums, nullptr, scanBlocks);
        scan_finish_kernel<<<nbl, TB, 0, stream>>>(deg, blockSums, rowStart, cursor, N, E);
        scatter_direct_kernel<<<ebl, TB, 0, stream>>>(src, dst, edge_attr, cursor,
                                                      src_perm, nullptr, ea_perm, E, 0);
        layer_gather_kernel<<<nbl, TB, 0, stream>>>(x, HID, ea_perm, src_perm, rowStart, W1, b1, hA, HS, N, 1);
        layer_gather_kernel<<<nbl, TB, 0, stream>>>(hA, HS, ea_perm, src_perm, rowStart, W2, b2, hB, HS, N, 1);
        layer_gather_kernel<<<nbl, TB, 0, stream>>>(hB, HS, ea_perm, src_perm, rowStart, W3, b3, hA, HS, N, 0);
        hIn = hA; hInStride = HS;
    } else {
        // ---- tier D: atomic fallback (minimal workspace) ----
        char* w2 = (char*)d_ws;
        float* dhA  = (float*)w2;
        float* dhB  = (float*)(w2 + szPad);
        float* dagg = (float*)(w2 + 2 * szPad);
        float* dsums = (float*)(w2 + 2 * szPad + szAgg);
        float* dcnts = dsums + NUM_GRAPHS * HID;
        sums = dsums; cnts = dcnts;

        hipMemsetAsync(dagg, 0, szAgg, stream);
        edge_kernel<<<ebl, TB, 0, stream>>>(x, HID, edge_attr, src, dst, dagg, E);
        node_kernel<<<nbl, TB, 0, stream>>>(x, HID, dagg, W1, b1, dhA, HS, N, 1);
        hipMemsetAsync(dagg, 0, szAgg, stream);
        edge_kernel<<<ebl, TB, 0, stream>>>(dhA, HS, edge_attr, src, dst, dagg, E);
        node_kernel<<<nbl, TB, 0, stream>>>(dhA, HS, dagg, W2, b2, dhB, HS, N, 1);
        hipMemsetAsync(dagg, 0, szAgg, stream);
        edge_kernel<<<ebl, TB, 0, stream>>>(dhB, HS, edge_attr, src, dst, dagg, E);
        node_kernel<<<nbl, TB, 0, stream>>>(dhB, HS, dagg, W3, b3, dhA, HS, N, 0);
        hIn = dhA; hInStride = HS;
    }

    hipMemsetAsync(sums, 0, (size_t)NUM_GRAPHS * HID * sizeof(float), stream);
    hipMemsetAsync(cnts, 0, (size_t)NUM_GRAPHS * sizeof(float), stream);
    pool_kernel<<<nbl, TB, 0, stream>>>(hIn, hInStride, batch, sums, cnts, N);
    out_kernel<<<(NUM_GRAPHS + TB - 1) / TB, TB, 0, stream>>>(sums, cnts, Wl, bl, (float*)d_out);
}